// Round 4
// baseline (125.605 us; speedup 1.0000x reference)
//
#include <hip/hip_runtime.h>
#include <math.h>

typedef __attribute__((ext_vector_type(8))) short short8;
typedef __attribute__((ext_vector_type(16))) float f32x16;
typedef __attribute__((ext_vector_type(4))) unsigned uintx4;

#define XT_ROWSH 8320          // shorts per padded xt row: 130 cols * 64 ci
#define XT_NSH   (130 * 8320)  // shorts per image in xt
#define XS_ROWB  4352          // LDS bytes per staged row: 34 cols * 128B

__device__ __forceinline__ short f2bf(float f) {
    union { float f; unsigned u; } v; v.f = f;
    unsigned r = (v.u + 0x7FFFu + ((v.u >> 16) & 1u)) >> 16;
    return (short)r;
}

// packed f32x2 -> bf16x2 (RNE on gfx950)
__device__ __forceinline__ unsigned cvt_pk_bf16(float lo, float hi) {
    unsigned r;
    asm("v_cvt_pk_bf16_f32 %0, %1, %2" : "=v"(r) : "v"(lo), "v"(hi));
    return r;
}

// Barrier draining LDS ops only (no vmcnt(0)).
__device__ __forceinline__ void bar_lds() {
    asm volatile("s_waitcnt lgkmcnt(0)" ::: "memory");
    __builtin_amdgcn_s_barrier();
}

__device__ __forceinline__ void gload_lds16(const void* g, void* l) {
    __builtin_amdgcn_global_load_lds(
        (const __attribute__((address_space(1))) unsigned*)g,
        (__attribute__((address_space(3))) unsigned*)l, 16, 0, 0);
}
__device__ __forceinline__ void gload_lds4(const void* g, void* l) {
    __builtin_amdgcn_global_load_lds(
        (const __attribute__((address_space(1))) unsigned*)g,
        (__attribute__((address_space(3))) unsigned*)l, 4, 0, 0);
}

// Pass 1: cvt+transpose x[n][ci][row][col] f32 -> xt[n][prow][pcol][ci] bf16
// with 1-row/1-col zero padding on all sides and within-column 16B-block
// swizzle (byte_off ^= (pcol&7)<<4) so pass 2 can global_load_lds linearly
// and ds_read through the same swizzle conflict-lite.
// Tail blocks (>= 16*130) build the weight A-fragments (old prep).
__global__ void cvt_t(const float* __restrict__ x, const float* __restrict__ w,
                      short* __restrict__ wfrag, short* __restrict__ xt)
{
    int blk = blockIdx.x;
    int t = threadIdx.x;
    if (blk >= 16 * 130) {   // ---- wfrag build: 128 blocks ----
        int idx = (blk - 16 * 130) * 256 + t;   // 0 .. 32767
        int j    = idx & 7;
        int lane = (idx >> 3) & 63;
        int q    = (idx >> 9) & 15;
        int p    = idx >> 13;
        int co = lane & 31, hf = lane >> 5;
        int ci = (q & 3) * 16 + hf * 8 + j;
        int tq = q >> 2, a = tq >> 1, b = tq & 1;
        int ph = p >> 1, pw = p & 1;
        int kh = 2 * a + 1 - ph, kw = 2 * b + 1 - pw;
        wfrag[idx] = f2bf(w[((ci * 32 + co) * 4 + kh) * 4 + kw]);
        return;
    }
    int n = blk / 130, prow = blk - n * 130;
    short* xr = xt + (size_t)n * XT_NSH + (size_t)prow * XT_ROWSH;

    if (prow == 0 || prow == 129) {          // pad rows: zero 16,640 B
        for (int i = t; i < 1040; i += 256)
            *(uintx4*)(xr + i * 8) = (uintx4)0;
        return;
    }
    if (t < 16) {                            // pad cols (pcol 0, 129): zero
        int side = t >> 3, o = t & 7;
        *(uintx4*)(xr + (side ? 129 * 64 : 0) + o * 8) = (uintx4)0;
    }
    int row = prow - 1;
    const float* xb = x + (size_t)n * 64 * 128 * 128 + row * 128;
    int col = t & 31, ci8 = (t >> 5) * 8;
    #pragma unroll
    for (int qd = 0; qd < 4; ++qd) {
        int c0 = col + 32 * qd, pcol = c0 + 1;
        const float* px = xb + (size_t)ci8 * 16384 + c0;
        float v[8];
        #pragma unroll
        for (int c = 0; c < 8; ++c) v[c] = px[(size_t)c * 16384];
        uintx4 u;
        u.x = cvt_pk_bf16(v[0], v[1]); u.y = cvt_pk_bf16(v[2], v[3]);
        u.z = cvt_pk_bf16(v[4], v[5]); u.w = cvt_pk_bf16(v[6], v[7]);
        int off = (ci8 * 2) ^ ((pcol & 7) << 4);   // swizzled within-col byte
        *(uintx4*)((char*)xr + (size_t)pcol * 128 + off) = u;
    }
}

// Pass 2: block = (n, col quarter jq, row strip st). Stage 10 padded rows
// (34 cols x 64 ci bf16) via 52 global_load_lds dwordx4 (linear copy of the
// pre-swizzled source), one __syncthreads, then the barrier-free 4-step
// MFMA body (both row-pairs interleaved, shared middle row), LDS reads
// through the swizzle. Non-atomic per-strip partials out.
__global__ __launch_bounds__(256, 3) void convt_mfma(
    const short* __restrict__ xt, const short* __restrict__ wfrag,
    const float* __restrict__ conv_b, float* __restrict__ partials)
{
    __shared__ short xs[10 * 34 * 64];       // 43,520 B, linear [r][colp][ci]
    __shared__ float minbuf[4][32];

    int blk = ((blockIdx.x & 7) << 7) | (blockIdx.x >> 3);  // XCD swizzle
    const int jq = blk & 3, st = (blk >> 2) & 15, n = blk >> 6;
    const int t  = threadIdx.x;
    const int i0 = st * 8;

    const int wv = t >> 6, lane = t & 63;    // wave = output parity (ph,pw)
    const int ph = wv >> 1, pw = wv & 1;
    const int ln = lane & 31, half = lane >> 5;

    // A fragments + conv-bias seed (C/D row = (reg&3)+8*(reg>>2)+4*half)
    short8 af[16];
    {
        const short8* wf = (const short8*)(wfrag + wv * 8192);
        #pragma unroll
        for (int q = 0; q < 16; ++q) af[q] = wf[q * 64 + lane];
    }
    float cb[16];
    #pragma unroll
    for (int reg = 0; reg < 16; ++reg)
        cb[reg] = conv_b[(reg & 3) + 8 * (reg >> 2) + 4 * half];

    // ---- stage: rows r = wv, wv+4, wv+8; 4x1KB + 1x256B per row ----
    {
        const char* xtn = (const char*)(xt + (size_t)n * XT_NSH);
        for (int r = wv; r < 10; r += 4) {
            const char* src = xtn + (size_t)(i0 + r) * (XT_ROWSH * 2)
                            + (size_t)(jq * 32) * 128;
            char* dst = (char*)xs + r * XS_ROWB;
            #pragma unroll
            for (int ch = 0; ch < 4; ++ch)
                gload_lds16(src + ch * 1024 + lane * 16, dst + ch * 1024);
            gload_lds4(src + 4096 + lane * 4, dst + 4096);
        }
    }
    __syncthreads();   // per-wave vmcnt(0) drain + barrier: LDS fully staged

    // ---- 4 compute steps: wave-local, barrier-free ----
    float osum = 0.f;
    #pragma unroll
    for (int k = 0; k < 4; ++k) {
        const int L0 = 2 * k + ph;           // rows L0, L0+1 (shared), L0+2
        f32x16 acc0, acc1;
        #pragma unroll
        for (int reg = 0; reg < 16; ++reg) { acc0[reg] = cb[reg]; acc1[reg] = cb[reg]; }
        __builtin_amdgcn_s_setprio(1);
        #pragma unroll
        for (int b = 0; b < 2; ++b) {
            int colp = ln + (pw - b) + 1;
            unsigned swz = (unsigned)(colp & 7) << 4;
            const char* r0 = (const char*)xs + (L0    ) * XS_ROWB + colp * 128;
            const char* r1 = (const char*)xs + (L0 + 1) * XS_ROWB + colp * 128;
            const char* r2 = (const char*)xs + (L0 + 2) * XS_ROWB + colp * 128;
            #pragma unroll
            for (int c = 0; c < 4; ++c) {
                unsigned offp = ((unsigned)(half * 16 + c * 32)) ^ swz;
                short8 Fs = *(const short8*)(r1 + offp);   // shared middle row
                acc0 = __builtin_amdgcn_mfma_f32_32x32x16_bf16(af[4*b+c],   Fs, acc0, 0, 0, 0);
                acc1 = __builtin_amdgcn_mfma_f32_32x32x16_bf16(af[8+4*b+c], Fs, acc1, 0, 0, 0);
                short8 F0 = *(const short8*)(r0 + offp);
                acc0 = __builtin_amdgcn_mfma_f32_32x32x16_bf16(af[8+4*b+c], F0, acc0, 0, 0, 0);
                short8 F2 = *(const short8*)(r2 + offp);
                acc1 = __builtin_amdgcn_mfma_f32_32x32x16_bf16(af[4*b+c],   F2, acc1, 0, 0, 0);
            }
        }
        __builtin_amdgcn_s_setprio(0);

        // tree min-reduce over co (16 acc rows), both row-pairs
        float mn0, mn1;
        {
            float a = fminf(fminf(acc0[0], acc0[1]), fminf(acc0[2], acc0[3]));
            float b2 = fminf(fminf(acc0[4], acc0[5]), fminf(acc0[6], acc0[7]));
            float c = fminf(fminf(acc0[8], acc0[9]), fminf(acc0[10], acc0[11]));
            float d = fminf(fminf(acc0[12], acc0[13]), fminf(acc0[14], acc0[15]));
            mn0 = fminf(fminf(a, b2), fminf(c, d));
            a = fminf(fminf(acc1[0], acc1[1]), fminf(acc1[2], acc1[3]));
            b2 = fminf(fminf(acc1[4], acc1[5]), fminf(acc1[6], acc1[7]));
            c = fminf(fminf(acc1[8], acc1[9]), fminf(acc1[10], acc1[11]));
            d = fminf(fminf(acc1[12], acc1[13]), fminf(acc1[14], acc1[15]));
            mn1 = fminf(fminf(a, b2), fminf(c, d));
        }
        mn0 = fminf(mn0, __shfl_xor(mn0, 32, 64));   // fold co halves
        mn1 = fminf(mn1, __shfl_xor(mn1, 32, 64));
        osum += mn0 + mn1;                           // height-sum (linear)
    }

    if (half == 0) minbuf[wv][ln] = osum;
    bar_lds();

    // combine ph=0 + ph=1 per pw -> one partial store per output column
    if (t < 64) {
        int c = t & 31, pwp = t >> 5;
        float v = minbuf[pwp][c] + minbuf[2 + pwp][c];
        int ow = ((jq * 32 + c) << 1) | pwp;
        partials[(size_t)st * 4096 + n * 256 + ow] = v;
    }
}

// Sum 16 strip-partials, GELU(tanh) + bias.
__global__ void finalize(const float* __restrict__ partials,
                         const float* __restrict__ bias, float* __restrict__ out)
{
    int idx = blockIdx.x * 256 + threadIdx.x;  // 0..4095
    float s = 0.f;
    #pragma unroll
    for (int st = 0; st < 16; ++st) s += partials[st * 4096 + idx];
    float u = 0.7978845608028654f * (s + 0.044715f * s * s * s);
    out[idx] = 0.5f * s * (1.f + tanhf(u)) + bias[0];
}

extern "C" void kernel_launch(void* const* d_in, const int* in_sizes, int n_in,
                              void* d_out, int out_size, void* d_ws, size_t ws_size,
                              hipStream_t stream) {
    const float* x      = (const float*)d_in[0];   // [16,64,128,128]
    const float* w      = (const float*)d_in[1];   // [64,32,4,4]
    const float* conv_b = (const float*)d_in[2];   // [32]
    const float* bias   = (const float*)d_in[3];   // [1]
    float* out = (float*)d_out;                    // 16*256

    short* wfrag    = (short*)d_ws;                        // 64 KB
    float* partials = (float*)((char*)d_ws + 65536);       // 256 KB
    short* xt       = (short*)((char*)d_ws + 65536 + 262144); // ~34.6 MB

    hipLaunchKernelGGL(cvt_t, dim3(16 * 130 + 128), dim3(256), 0, stream,
                       x, w, wfrag, xt);
    hipLaunchKernelGGL(convt_mfma, dim3(16 * 16 * 4), dim3(256), 0, stream,
                       xt, wfrag, conv_b, partials);
    hipLaunchKernelGGL(finalize, dim3(16), dim3(256), 0, stream,
                       partials, bias, out);
}